// Round 1
// baseline (250.155 us; speedup 1.0000x reference)
//
#include <hip/hip_runtime.h>
#include <hip/hip_bf16.h>

typedef unsigned short bf16_t;
typedef __attribute__((ext_vector_type(8))) short bf16x8;
typedef __attribute__((ext_vector_type(4))) float f32x4;

#define MFMA16(a, b, c) __builtin_amdgcn_mfma_f32_16x16x32_bf16((a), (b), (c), 0, 0, 0)

__device__ __forceinline__ bf16_t f2bf(float f) {
  union { float f; unsigned u; } v; v.f = f;
  unsigned u = v.u;
  u += 0x7FFFu + ((u >> 16) & 1u);
  return (bf16_t)(u >> 16);
}

__device__ __forceinline__ void gld_lds16(const void* g, void* l) {
  __builtin_amdgcn_global_load_lds(
      (const __attribute__((address_space(1))) unsigned int*)g,
      (__attribute__((address_space(3))) unsigned int*)l, 16, 0, 0);
}

// ---------------- elementwise fp32 -> bf16 (8/thread) ----------------
__global__ __launch_bounds__(256) void k_f32_to_bf16(const float* __restrict__ in,
                                                     bf16_t* __restrict__ out, int n8) {
  int i = blockIdx.x * 256 + threadIdx.x;
  if (i >= n8) return;
  const float4* p = (const float4*)in + (size_t)i * 2;
  float4 a = p[0], b = p[1];
  bf16x8 o;
  o[0] = (short)f2bf(a.x); o[1] = (short)f2bf(a.y); o[2] = (short)f2bf(a.z); o[3] = (short)f2bf(a.w);
  o[4] = (short)f2bf(b.x); o[5] = (short)f2bf(b.y); o[6] = (short)f2bf(b.z); o[7] = (short)f2bf(b.w);
  *((bf16x8*)out + i) = o;
}

// ---------------- transpose + convert: W[K][N] f32 -> Wt[N][K] bf16 ----------------
__global__ __launch_bounds__(256) void k_transpose_bf16(const float* __restrict__ W,
                                                        bf16_t* __restrict__ Wt, int K, int N) {
  __shared__ bf16_t t[64][65];
  int n0 = blockIdx.x * 64, k0 = blockIdx.y * 64;
  int tid = threadIdx.x;
#pragma unroll
  for (int p = 0; p < 16; ++p) {
    int lin = p * 256 + tid;
    int r = lin >> 6, c = lin & 63;
    t[r][c] = f2bf(W[(size_t)(k0 + r) * N + n0 + c]);
  }
  __syncthreads();
#pragma unroll
  for (int p = 0; p < 16; ++p) {
    int lin = p * 256 + tid;
    int nr = lin >> 6, kc = lin & 63;
    Wt[(size_t)(n0 + nr) * K + k0 + kc] = t[kc][nr];
  }
}

// ---------------- GEMM-BT (m97 structure): C[M][N] = A[M][K] @ Bt[N][K]^T + bias ----------------
template <bool BF16OUT>
__global__ __launch_bounds__(256) void k_gemm_bt(const bf16_t* __restrict__ A,
                                                 const bf16_t* __restrict__ Bt,
                                                 const float* __restrict__ bias,
                                                 void* __restrict__ Cout, int M, int N, int K) {
  __shared__ bf16_t Al[128 * 32];
  __shared__ bf16_t Bl[128 * 32];
  const int tid = threadIdx.x;
  const int lane = tid & 63;
  const int wid = tid >> 6;
  const int wm = wid >> 1, wn = wid & 1;
  const int m0 = blockIdx.y * 128, n0 = blockIdx.x * 128;
  const int lr = lane & 15;  // fragment row/col within 16
  const int lk = lane >> 4;  // k-group

  f32x4 acc[4][4] = {};

  for (int k0 = 0; k0 < K; k0 += 32) {
    __syncthreads();
#pragma unroll
    for (int p = 0; p < 2; ++p) {
      int o = p * 4096 + tid * 16;
      int row = o >> 6, cb = o & 63;
      gld_lds16((const char*)A + ((size_t)(m0 + row) * K + k0) * 2 + cb, (char*)Al + o);
      gld_lds16((const char*)Bt + ((size_t)(n0 + row) * K + k0) * 2 + cb, (char*)Bl + o);
    }
    __syncthreads();
    bf16x8 af[4], bfr[4];
#pragma unroll
    for (int i = 0; i < 4; ++i) {
      af[i]  = *(const bf16x8*)(Al + ((wm * 64 + i * 16 + lr) * 32 + lk * 8));
      bfr[i] = *(const bf16x8*)(Bl + ((wn * 64 + i * 16 + lr) * 32 + lk * 8));
    }
#pragma unroll
    for (int i = 0; i < 4; ++i)
#pragma unroll
      for (int j = 0; j < 4; ++j)
        acc[i][j] = MFMA16(af[i], bfr[j], acc[i][j]);
  }

#pragma unroll
  for (int i = 0; i < 4; ++i) {
    int grow = m0 + wm * 64 + i * 16 + lk * 4;
#pragma unroll
    for (int j = 0; j < 4; ++j) {
      int gcol = n0 + wn * 64 + j * 16 + lr;
      float bv = bias[gcol];
#pragma unroll
      for (int r = 0; r < 4; ++r) {
        float v = acc[i][j][r] + bv;
        size_t off = (size_t)(grow + r) * N + gcol;
        if (BF16OUT)
          ((bf16_t*)Cout)[off] = f2bf(v);
        else
          ((float*)Cout)[off] = v;
      }
    }
  }
}

// ---------------- fused causal attention ----------------
// grid: (S/128, B*H); block 256 = 4 waves, wave w owns q rows [qt*128+w*32, +32)
// qkv: [B*S][3*D] bf16; Q at col h*64, K at 1024+h*64, V at 2048+h*64
// score out: [B*S][D] bf16
__global__ __launch_bounds__(256) void k_attn(const bf16_t* __restrict__ qkv,
                                              bf16_t* __restrict__ score) {
  __shared__ bf16_t Vt[64 * 64];       // [d][kv], XOR-swizzled
  __shared__ bf16_t Pl[4][32 * 64];    // per-wave P [qrow][kv], XOR-swizzled
  const int tid = threadIdx.x;
  const int lane = tid & 63;
  const int w = tid >> 6;
  const int lr = lane & 15, lk = lane >> 4;
  const int qt = blockIdx.x;
  const int bh = blockIdx.y;
  const int b = bh >> 4, h = bh & 15;

  const bf16_t* Qb = qkv + (size_t)b * 2048 * 3072 + h * 64;
  const bf16_t* Kb = Qb + 1024;
  const bf16_t* Vb = Qb + 2048;

  const int qr0 = qt * 128 + w * 32;

  // hoist Q fragments
  bf16x8 qf[2][2];
#pragma unroll
  for (int mr = 0; mr < 2; ++mr)
#pragma unroll
    for (int ks = 0; ks < 2; ++ks)
      qf[mr][ks] = *(const bf16x8*)(Qb + (size_t)(qr0 + mr * 16 + lr) * 3072 + ks * 32 + lk * 8);

  f32x4 o[2][4] = {};
  float mrun[2][4], lrun[2][4];
#pragma unroll
  for (int i = 0; i < 2; ++i)
#pragma unroll
    for (int r = 0; r < 4; ++r) { mrun[i][r] = -INFINITY; lrun[i][r] = 0.f; }

  const float sc = 0.125f * 1.44269504089f;  // 1/sqrt(64) * log2(e)

  const int jt_end = qt * 2 + 2;
  for (int jt = 0; jt < jt_end; ++jt) {
    const int kv0 = jt * 64;
    __syncthreads();  // all waves done reading Vt of previous tile
    // stage V^T (swizzled) cooperatively
#pragma unroll
    for (int p = 0; p < 2; ++p) {
      int e = (p * 256 + tid) * 8;
      int kv = e >> 6, d0 = e & 63;
      bf16x8 v8 = *(const bf16x8*)(Vb + (size_t)(kv0 + kv) * 3072 + d0);
#pragma unroll
      for (int j = 0; j < 8; ++j) {
        int d = d0 + j;
        int addr = d * 128 + kv * 2;
        addr ^= (d & 7) << 4;
        *(bf16_t*)((char*)Vt + addr) = (bf16_t)v8[j];
      }
    }

    const bool active = (kv0 <= qr0 + 31);
    if (active) {
      // S = Q K^T (K fragments direct from global, L2-resident)
      f32x4 s[2][4];
#pragma unroll
      for (int nc = 0; nc < 4; ++nc) {
        const bf16_t* krow = Kb + (size_t)(kv0 + nc * 16 + lr) * 3072;
        bf16x8 kf0 = *(const bf16x8*)(krow + lk * 8);
        bf16x8 kf1 = *(const bf16x8*)(krow + 32 + lk * 8);
#pragma unroll
        for (int mr = 0; mr < 2; ++mr) {
          f32x4 z = {};
          z = MFMA16(qf[mr][0], kf0, z);
          z = MFMA16(qf[mr][1], kf1, z);
          s[mr][nc] = z;
        }
      }
      // scale (log2 domain) + causal mask
      const bool need_mask = (kv0 + 63 > qr0);
#pragma unroll
      for (int mr = 0; mr < 2; ++mr)
#pragma unroll
        for (int nc = 0; nc < 4; ++nc)
#pragma unroll
          for (int r = 0; r < 4; ++r) {
            float v = s[mr][nc][r] * sc;
            if (need_mask) {
              int q = qr0 + mr * 16 + lk * 4 + r;
              int kvi = kv0 + nc * 16 + lr;
              if (kvi > q) v = -INFINITY;
            }
            s[mr][nc][r] = v;
          }
      // online softmax (base-2)
#pragma unroll
      for (int mr = 0; mr < 2; ++mr) {
#pragma unroll
        for (int r = 0; r < 4; ++r) {
          float rm = fmaxf(fmaxf(s[mr][0][r], s[mr][1][r]), fmaxf(s[mr][2][r], s[mr][3][r]));
#pragma unroll
          for (int off = 1; off < 16; off <<= 1)
            rm = fmaxf(rm, __shfl_xor(rm, off, 16));
          float mnew = fmaxf(mrun[mr][r], rm);
          float alpha = exp2f(mrun[mr][r] - mnew);
          float ps = 0.f;
#pragma unroll
          for (int nc = 0; nc < 4; ++nc) {
            float p = exp2f(s[mr][nc][r] - mnew);
            s[mr][nc][r] = p;
            ps += p;
          }
#pragma unroll
          for (int off = 1; off < 16; off <<= 1)
            ps += __shfl_xor(ps, off, 16);
          lrun[mr][r] = lrun[mr][r] * alpha + ps;
          mrun[mr][r] = mnew;
#pragma unroll
          for (int d = 0; d < 4; ++d) o[mr][d][r] *= alpha;
        }
      }
      // P -> per-wave LDS (bf16, swizzled)
      bf16_t* Pw = Pl[w];
#pragma unroll
      for (int mr = 0; mr < 2; ++mr)
#pragma unroll
        for (int nc = 0; nc < 4; ++nc)
#pragma unroll
          for (int r = 0; r < 4; ++r) {
            int row = mr * 16 + lk * 4 + r;
            int col = nc * 16 + lr;
            int addr = row * 128 + col * 2;
            addr ^= (row & 7) << 4;
            *(bf16_t*)((char*)Pw + addr) = f2bf(s[mr][nc][r]);
          }
    }
    __syncthreads();  // Vt staged + P visible
    if (active) {
      bf16x8 pa[2][2];
#pragma unroll
      for (int mr = 0; mr < 2; ++mr)
#pragma unroll
        for (int ks = 0; ks < 2; ++ks) {
          int row = mr * 16 + lr;
          int addr = row * 128 + ks * 64 + lk * 16;
          addr ^= (row & 7) << 4;
          pa[mr][ks] = *(const bf16x8*)((const char*)Pl[w] + addr);
        }
#pragma unroll
      for (int db = 0; db < 4; ++db) {
#pragma unroll
        for (int ks = 0; ks < 2; ++ks) {
          int d = db * 16 + lr;
          int addr = d * 128 + ks * 64 + lk * 16;
          addr ^= (d & 7) << 4;
          bf16x8 vb = *(const bf16x8*)((const char*)Vt + addr);
#pragma unroll
          for (int mr = 0; mr < 2; ++mr)
            o[mr][db] = MFMA16(pa[mr][ks], vb, o[mr][db]);
        }
      }
    }
  }

  // epilogue: score[b*S+q][h*64+d] = o / l
#pragma unroll
  for (int mr = 0; mr < 2; ++mr)
#pragma unroll
    for (int db = 0; db < 4; ++db)
#pragma unroll
      for (int r = 0; r < 4; ++r) {
        int qrow = qr0 + mr * 16 + lk * 4 + r;
        float v = o[mr][db][r] / lrun[mr][r];
        score[(size_t)(b * 2048 + qrow) * 1024 + h * 64 + db * 16 + lr] = f2bf(v);
      }
}

extern "C" void kernel_launch(void* const* d_in, const int* in_sizes, int n_in,
                              void* d_out, int out_size, void* d_ws, size_t ws_size,
                              hipStream_t stream) {
  const float* X  = (const float*)d_in[0];  // [2,2048,1024]
  const float* Wa = (const float*)d_in[1];  // [1024,3072]
  const float* ba = (const float*)d_in[2];  // [3072]
  const float* Wp = (const float*)d_in[3];  // [1024,1024]
  const float* bp = (const float*)d_in[4];  // [1024]
  float* out = (float*)d_out;               // [2,2048,1024] fp32

  char* ws = (char*)d_ws;
  bf16_t* Xb  = (bf16_t*)ws;                       // 8 MiB (reused as score after QKV GEMM)
  bf16_t* WaT = (bf16_t*)(ws + (size_t)(8u << 20));   // 6 MiB: W_attn^T [3072][1024]
  bf16_t* WpT = (bf16_t*)(ws + (size_t)(14u << 20));  // 2 MiB: W_proj^T [1024][1024]
  bf16_t* QKV = (bf16_t*)(ws + (size_t)(16u << 20));  // 24 MiB: [4096][3072]
  bf16_t* S_  = Xb;

  k_f32_to_bf16<<<2048, 256, 0, stream>>>(X, Xb, 4096 * 1024 / 8);
  k_transpose_bf16<<<dim3(48, 16), 256, 0, stream>>>(Wa, WaT, 1024, 3072);
  k_transpose_bf16<<<dim3(16, 16), 256, 0, stream>>>(Wp, WpT, 1024, 1024);
  k_gemm_bt<true><<<dim3(24, 32), 256, 0, stream>>>(Xb, WaT, ba, QKV, 4096, 3072, 1024);
  k_attn<<<dim3(16, 32), 256, 0, stream>>>(QKV, S_);
  k_gemm_bt<false><<<dim3(8, 32), 256, 0, stream>>>(S_, WpT, bp, out, 4096, 1024, 1024);
}

// Round 4
// 185.903 us; speedup vs baseline: 1.3456x; 1.3456x over previous
//
#include <hip/hip_runtime.h>
#include <hip/hip_bf16.h>

typedef unsigned short bf16_t;
typedef __attribute__((ext_vector_type(8))) short bf16x8;
typedef __attribute__((ext_vector_type(4))) float f32x4;

#define MFMA16(a, b, c) __builtin_amdgcn_mfma_f32_16x16x32_bf16((a), (b), (c), 0, 0, 0)

__device__ __forceinline__ bf16_t f2bf(float f) {
  union { float f; unsigned u; } v; v.f = f;
  unsigned u = v.u;
  u += 0x7FFFu + ((u >> 16) & 1u);
  return (bf16_t)(u >> 16);
}

__device__ __forceinline__ void gld_lds16(const void* g, void* l) {
  __builtin_amdgcn_global_load_lds(
      (const __attribute__((address_space(1))) unsigned int*)g,
      (__attribute__((address_space(3))) unsigned int*)l, 16, 0, 0);
}

// ---------------- elementwise fp32 -> bf16 (8/thread) ----------------
__global__ __launch_bounds__(256) void k_f32_to_bf16(const float* __restrict__ in,
                                                     bf16_t* __restrict__ out, int n8) {
  int i = blockIdx.x * 256 + threadIdx.x;
  if (i >= n8) return;
  const float4* p = (const float4*)in + (size_t)i * 2;
  float4 a = p[0], b = p[1];
  bf16x8 o;
  o[0] = (short)f2bf(a.x); o[1] = (short)f2bf(a.y); o[2] = (short)f2bf(a.z); o[3] = (short)f2bf(a.w);
  o[4] = (short)f2bf(b.x); o[5] = (short)f2bf(b.y); o[6] = (short)f2bf(b.z); o[7] = (short)f2bf(b.w);
  *((bf16x8*)out + i) = o;
}

// ---------------- transpose + convert: W[K][N] f32 -> Wt[N][K] bf16 ----------------
__global__ __launch_bounds__(256) void k_transpose_bf16(const float* __restrict__ W,
                                                        bf16_t* __restrict__ Wt, int K, int N) {
  __shared__ bf16_t t[64][65];
  int n0 = blockIdx.x * 64, k0 = blockIdx.y * 64;
  int tid = threadIdx.x;
#pragma unroll
  for (int p = 0; p < 16; ++p) {
    int lin = p * 256 + tid;
    int r = lin >> 6, c = lin & 63;
    t[r][c] = f2bf(W[(size_t)(k0 + r) * N + n0 + c]);
  }
  __syncthreads();
#pragma unroll
  for (int p = 0; p < 16; ++p) {
    int lin = p * 256 + tid;
    int nr = lin >> 6, kc = lin & 63;
    Wt[(size_t)(n0 + nr) * K + k0 + kc] = t[kc][nr];
  }
}

// ---------------- GEMM-BT (m97 structure): C[M][N] = A[M][K] @ Bt[N][K]^T + bias ----------------
template <bool BF16OUT>
__global__ __launch_bounds__(256) void k_gemm_bt(const bf16_t* __restrict__ A,
                                                 const bf16_t* __restrict__ Bt,
                                                 const float* __restrict__ bias,
                                                 void* __restrict__ Cout, int M, int N, int K) {
  __shared__ bf16_t Al[128 * 32];
  __shared__ bf16_t Bl[128 * 32];
  const int tid = threadIdx.x;
  const int lane = tid & 63;
  const int wid = tid >> 6;
  const int wm = wid >> 1, wn = wid & 1;
  const int m0 = blockIdx.y * 128, n0 = blockIdx.x * 128;
  const int lr = lane & 15;
  const int lk = lane >> 4;

  f32x4 acc[4][4] = {};

  for (int k0 = 0; k0 < K; k0 += 32) {
    __syncthreads();
#pragma unroll
    for (int p = 0; p < 2; ++p) {
      int o = p * 4096 + tid * 16;
      int row = o >> 6, cb = o & 63;
      gld_lds16((const char*)A + ((size_t)(m0 + row) * K + k0) * 2 + cb, (char*)Al + o);
      gld_lds16((const char*)Bt + ((size_t)(n0 + row) * K + k0) * 2 + cb, (char*)Bl + o);
    }
    __syncthreads();
    bf16x8 af[4], bfr[4];
#pragma unroll
    for (int i = 0; i < 4; ++i) {
      af[i]  = *(const bf16x8*)(Al + ((wm * 64 + i * 16 + lr) * 32 + lk * 8));
      bfr[i] = *(const bf16x8*)(Bl + ((wn * 64 + i * 16 + lr) * 32 + lk * 8));
    }
#pragma unroll
    for (int i = 0; i < 4; ++i)
#pragma unroll
      for (int j = 0; j < 4; ++j)
        acc[i][j] = MFMA16(af[i], bfr[j], acc[i][j]);
  }

#pragma unroll
  for (int i = 0; i < 4; ++i) {
    int grow = m0 + wm * 64 + i * 16 + lk * 4;
#pragma unroll
    for (int j = 0; j < 4; ++j) {
      int gcol = n0 + wn * 64 + j * 16 + lr;
      float bv = bias[gcol];
#pragma unroll
      for (int r = 0; r < 4; ++r) {
        float v = acc[i][j][r] + bv;
        size_t off = (size_t)(grow + r) * N + gcol;
        if (BF16OUT)
          ((bf16_t*)Cout)[off] = f2bf(v);
        else
          ((float*)Cout)[off] = v;
      }
    }
  }
}

// ---------------- fused causal attention (paired q-tiles, prefetched) ----------------
// Grid: 512 blocks = 16 pairs x 32 (b,h). Block (pr,bh) runs q-tile pr then 31-pr,
// 64 q-rows each (wave w owns rows [qt*64 + w*16, +16)). Steps = (pr+1)+(32-pr) = 33
// for every block -> perfectly balanced, no causal tail.
// Per step: write Vt from regs (prefetched last step), issue next V/K loads,
// QK^T from prefetched K-frags, online softmax, P->LDS, PV. Raw s_barrier
// (+lgkmcnt only) keeps vmem prefetch in flight across barriers.
// V path / P path / softmax identical to the R1-verified kernel.
__global__ __launch_bounds__(256) void k_attn(const bf16_t* __restrict__ qkv,
                                              bf16_t* __restrict__ score) {
  __shared__ bf16_t Vt[64 * 64];     // [d][kv] XOR-swizzled, 8 KiB
  __shared__ bf16_t Pl[4][16 * 64];  // per-wave P [qrow][kv] XOR-swizzled, 8 KiB
  const int tid = threadIdx.x;
  const int lane = tid & 63;
  const int w = tid >> 6;
  const int lr = lane & 15, lk = lane >> 4;

  const int flat = blockIdx.x;
  const int pr = flat >> 5;   // pair index 0..15
  const int bh = flat & 31;   // same bh -> same XCD (32 % 8 == 0): K/V L2 locality
  const int b = bh >> 4, h = bh & 15;

  const bf16_t* Qb = qkv + (size_t)b * 2048 * 3072 + h * 64;
  const bf16_t* Kb = Qb + 1024;
  const bf16_t* Vb = Qb + 2048;

  const float sc = 0.125f * 1.44269504089f;  // 1/sqrt(64) * log2(e)

  // V staging coords (R1-verified): pass p stages elems e=(p*256+tid)*8
  int vkv[2], vd0[2];
#pragma unroll
  for (int p = 0; p < 2; ++p) {
    int e = (p * 256 + tid) * 8;
    vkv[p] = e >> 6;
    vd0[p] = e & 63;
  }

  for (int ph = 0; ph < 2; ++ph) {
    const int qt = ph ? (31 - pr) : pr;
    const int qr0 = qt * 64 + w * 16;
    const int jtEnd = qt + 1;

    // hoist Q fragments
    bf16x8 qf[2];
#pragma unroll
    for (int ks = 0; ks < 2; ++ks)
      qf[ks] = *(const bf16x8*)(Qb + (size_t)(qr0 + lr) * 3072 + ks * 32 + lk * 8);

    f32x4 o[4] = {};
    float mm[4], ll[4];
#pragma unroll
    for (int r = 0; r < 4; ++r) { mm[r] = -INFINITY; ll[r] = 0.f; }

    // prologue: prefetch tile 0 into regs
    bf16x8 vreg[2], kf[4][2];
#pragma unroll
    for (int p = 0; p < 2; ++p)
      vreg[p] = *(const bf16x8*)(Vb + (size_t)vkv[p] * 3072 + vd0[p]);
#pragma unroll
    for (int nc = 0; nc < 4; ++nc)
#pragma unroll
      for (int ks = 0; ks < 2; ++ks)
        kf[nc][ks] = *(const bf16x8*)(Kb + (size_t)(nc * 16 + lr) * 3072 + ks * 32 + lk * 8);

    for (int jt = 0; jt < jtEnd; ++jt) {
      const int kv0 = jt * 64;
      // barrier1: all waves done reading Vt of previous step (keeps vmem in flight)
      asm volatile("s_waitcnt lgkmcnt(0)" ::: "memory");
      __builtin_amdgcn_s_barrier();
      // write Vt from prefetched regs (scalar swizzled writes, R1-verified)
#pragma unroll
      for (int p = 0; p < 2; ++p)
#pragma unroll
        for (int j = 0; j < 8; ++j) {
          int d = vd0[p] + j;
          int addr = (d * 128 + vkv[p] * 2) ^ ((d & 7) << 4);
          *(bf16_t*)((char*)Vt + addr) = (bf16_t)vreg[p][j];
        }
      // prefetch next tile (clamped in-bounds; garbage unused on last step)
      const int kvn = (kv0 + 64 < 2048) ? (kv0 + 64) : 1984;
      bf16x8 vregN[2], kfN[4][2];
#pragma unroll
      for (int p = 0; p < 2; ++p)
        vregN[p] = *(const bf16x8*)(Vb + (size_t)(kvn + vkv[p]) * 3072 + vd0[p]);
#pragma unroll
      for (int nc = 0; nc < 4; ++nc)
#pragma unroll
        for (int ks = 0; ks < 2; ++ks)
          kfN[nc][ks] = *(const bf16x8*)(Kb + (size_t)(kvn + nc * 16 + lr) * 3072 + ks * 32 + lk * 8);

      const bool active = (kv0 <= qr0 + 15);
      if (active) {
        // S = Q K^T from register K-fragments
        f32x4 s[4];
#pragma unroll
        for (int nc = 0; nc < 4; ++nc) {
          f32x4 z = {};
          z = MFMA16(qf[0], kf[nc][0], z);
          z = MFMA16(qf[1], kf[nc][1], z);
          s[nc] = z;
        }
        // scale (log2 domain) + causal mask
        const bool need_mask = (kv0 + 63 > qr0);
#pragma unroll
        for (int nc = 0; nc < 4; ++nc)
#pragma unroll
          for (int r = 0; r < 4; ++r) {
            float v = s[nc][r] * sc;
            if (need_mask) {
              int q = qr0 + lk * 4 + r;
              int kvi = kv0 + nc * 16 + lr;
              if (kvi > q) v = -INFINITY;
            }
            s[nc][r] = v;
          }
        // online softmax (base-2), reduce over the 16 lanes sharing lk
#pragma unroll
        for (int r = 0; r < 4; ++r) {
          float rm = fmaxf(fmaxf(s[0][r], s[1][r]), fmaxf(s[2][r], s[3][r]));
#pragma unroll
          for (int off = 1; off < 16; off <<= 1)
            rm = fmaxf(rm, __shfl_xor(rm, off, 16));
          float mnew = fmaxf(mm[r], rm);
          float alpha = exp2f(mm[r] - mnew);
          float ps = 0.f;
#pragma unroll
          for (int nc = 0; nc < 4; ++nc) {
            float p = exp2f(s[nc][r] - mnew);
            s[nc][r] = p;
            ps += p;
          }
#pragma unroll
          for (int off = 1; off < 16; off <<= 1)
            ps += __shfl_xor(ps, off, 16);
          ll[r] = ll[r] * alpha + ps;
          mm[r] = mnew;
#pragma unroll
          for (int d = 0; d < 4; ++d) o[d][r] *= alpha;
        }
        // P -> per-wave LDS (bf16, swizzled)
        bf16_t* Pw = Pl[w];
#pragma unroll
        for (int nc = 0; nc < 4; ++nc)
#pragma unroll
          for (int r = 0; r < 4; ++r) {
            int row = lk * 4 + r;
            int col = nc * 16 + lr;
            int addr = (row * 128 + col * 2) ^ ((row & 7) << 4);
            *(bf16_t*)((char*)Pw + addr) = f2bf(s[nc][r]);
          }
      }
      // barrier2: Vt + P writes visible (lgkm only; prefetch stays in flight)
      asm volatile("s_waitcnt lgkmcnt(0)" ::: "memory");
      __builtin_amdgcn_s_barrier();
      if (active) {
        bf16x8 pa[2];
#pragma unroll
        for (int ks = 0; ks < 2; ++ks) {
          int addr = (lr * 128 + ks * 64 + lk * 16) ^ ((lr & 7) << 4);
          pa[ks] = *(const bf16x8*)((const char*)Pl[w] + addr);
        }
#pragma unroll
        for (int db = 0; db < 4; ++db)
#pragma unroll
          for (int ks = 0; ks < 2; ++ks) {
            int d = db * 16 + lr;
            int addr = (d * 128 + ks * 64 + lk * 16) ^ ((d & 7) << 4);
            bf16x8 vb = *(const bf16x8*)((const char*)Vt + addr);
            o[db] = MFMA16(pa[ks], vb, o[db]);
          }
      }
      // rotate prefetch
#pragma unroll
      for (int p = 0; p < 2; ++p) vreg[p] = vregN[p];
#pragma unroll
      for (int nc = 0; nc < 4; ++nc)
#pragma unroll
        for (int ks = 0; ks < 2; ++ks) kf[nc][ks] = kfN[nc][ks];
    }

    // epilogue for this phase
#pragma unroll
    for (int db = 0; db < 4; ++db)
#pragma unroll
      for (int r = 0; r < 4; ++r) {
        int qrow = qr0 + lk * 4 + r;
        float v = o[db][r] / ll[r];
        score[(size_t)(b * 2048 + qrow) * 1024 + h * 64 + db * 16 + lr] = f2bf(v);
      }
  }
}

extern "C" void kernel_launch(void* const* d_in, const int* in_sizes, int n_in,
                              void* d_out, int out_size, void* d_ws, size_t ws_size,
                              hipStream_t stream) {
  const float* X  = (const float*)d_in[0];  // [2,2048,1024]
  const float* Wa = (const float*)d_in[1];  // [1024,3072]
  const float* ba = (const float*)d_in[2];  // [3072]
  const float* Wp = (const float*)d_in[3];  // [1024,1024]
  const float* bp = (const float*)d_in[4];  // [1024]
  float* out = (float*)d_out;               // [2,2048,1024] fp32

  char* ws = (char*)d_ws;
  bf16_t* Xb  = (bf16_t*)ws;                          // 8 MiB (reused as score)
  bf16_t* WaT = (bf16_t*)(ws + (size_t)(8u << 20));   // 6 MiB: W_attn^T [3072][1024]
  bf16_t* WpT = (bf16_t*)(ws + (size_t)(14u << 20));  // 2 MiB: W_proj^T [1024][1024]
  bf16_t* QKV = (bf16_t*)(ws + (size_t)(16u << 20));  // 24 MiB: [4096][3072]
  bf16_t* S_  = Xb;

  k_f32_to_bf16<<<2048, 256, 0, stream>>>(X, Xb, 4096 * 1024 / 8);
  k_transpose_bf16<<<dim3(48, 16), 256, 0, stream>>>(Wa, WaT, 1024, 3072);
  k_transpose_bf16<<<dim3(16, 16), 256, 0, stream>>>(Wp, WpT, 1024, 1024);
  k_gemm_bt<true><<<dim3(24, 32), 256, 0, stream>>>(Xb, WaT, ba, QKV, 4096, 3072, 1024);
  k_attn<<<512, 256, 0, stream>>>(QKV, S_);
  k_gemm_bt<false><<<dim3(8, 32), 256, 0, stream>>>(S_, WpT, bp, out, 4096, 1024, 1024);
}